// Round 10
// baseline (13952.574 us; speedup 1.0000x reference)
//
#include <hip/hip_runtime.h>
#include <math.h>

#define N_  2048
#define T_  200
#define D_  16
#define H_  64
#define C2_ 128
#define NTHR 1024
#define NBLK 256

// X slot: [128][2048] bf16 (premultiplied [hW+b|cW+b]^T) + 4KB guard
#define SLOT_USH ((size_t)C2_ * N_ + 2048)

typedef unsigned short ushort_t;
typedef short bf16x8 __attribute__((ext_vector_type(8)));
typedef float f32x4 __attribute__((ext_vector_type(4)));

// ---- f32 weight blob (float offsets), matrices TRANSPOSED [out][in] ----
#define F_HC 0
#define F_HP 4096
#define F_CC 8192
#define F_CP 12288
#define F_GH 16384
#define F_GC 20480
#define F_R  24576
#define F_K  40960
#define F_B  45056    // bh(64) bc(64) bgh(64) bgc(64) bl(256)
#define FBLOB_F32 47616

__device__ __forceinline__ float sig_(float x) {
    return __fdividef(1.0f, 1.0f + __expf(-x));
}
__device__ __forceinline__ float tanh_(float x) {
    float e = __expf(-2.0f * fabsf(x));
    float t = __fdividef(1.0f - e, 1.0f + e);
    return copysignf(t, x);
}
__device__ __forceinline__ ushort_t f2bf(float f) {
    unsigned u = __float_as_uint(f);
    u = (u + 0x7FFFu + ((u >> 16) & 1u)) >> 16;
    return (ushort_t)u;
}
__device__ __forceinline__ void gload16(const void* g, void* l) {
    __builtin_amdgcn_global_load_lds(
        (const __attribute__((address_space(1))) unsigned int*)g,
        (__attribute__((address_space(3))) unsigned int*)l, 16, 0, 0);
}

// ---- A fp32 -> bf16; zero the two barrier counters ----
__global__ __launch_bounds__(256) void convert_A_kernel(
    const float* __restrict__ A, ushort_t* __restrict__ Abf,
    unsigned* __restrict__ cnt)
{
    if (blockIdx.x == 0 && threadIdx.x < 32)
        __hip_atomic_store(cnt + threadIdx.x, 0u, __ATOMIC_RELAXED, __HIP_MEMORY_SCOPE_AGENT);
    size_t i = ((size_t)blockIdx.x * 256 + threadIdx.x) * 4;
    float4 v = *(const float4*)(A + i);
    ushort4 o;
    o.x = f2bf(v.x); o.y = f2bf(v.y); o.z = f2bf(v.z); o.w = f2bf(v.w);
    *(ushort4*)(Abf + i) = o;
}

// ---- pack all weights f32 transposed ----
__global__ __launch_bounds__(256) void convert_Wf_kernel(
    const float* __restrict__ Whc, const float* __restrict__ Whp,
    const float* __restrict__ Wcc, const float* __restrict__ Wcp,
    const float* __restrict__ Wgh, const float* __restrict__ Wgc,
    const float* __restrict__ R,   const float* __restrict__ Kw,
    const float* __restrict__ bh,  const float* __restrict__ bc,
    const float* __restrict__ bgh, const float* __restrict__ bgc,
    const float* __restrict__ bl,
    float* __restrict__ fb)
{
    const int stride = gridDim.x * 256;
    const int gid = blockIdx.x * 256 + threadIdx.x;
    for (int idx = gid; idx < 4096; idx += stride) {
        int k = idx >> 6, c = idx & 63;
        int dst = c * 64 + k;
        fb[F_HC + dst] = Whc[idx];
        fb[F_HP + dst] = Whp[idx];
        fb[F_CC + dst] = Wcc[idx];
        fb[F_CP + dst] = Wcp[idx];
        fb[F_GH + dst] = Wgh[idx];
        fb[F_GC + dst] = Wgc[idx];
    }
    for (int idx = gid; idx < 16384; idx += stride) {
        int k = idx >> 8, gc = idx & 255;
        fb[F_R + gc * 64 + k] = R[idx];
    }
    for (int idx = gid; idx < 4096; idx += stride) {
        int d = idx >> 8, gc = idx & 255;
        fb[F_K + gc * 16 + d] = Kw[idx];
    }
    if (gid < 64) {
        fb[F_B + gid]       = bh[gid];
        fb[F_B + 64 + gid]  = bc[gid];
        fb[F_B + 128 + gid] = bgh[gid];
        fb[F_B + 192 + gid] = bgc[gid];
    }
    if (gid < 256) fb[F_B + 256 + gid] = bl[gid];
}

// ---- Prologue (R6): X_0^T = premultiplied, bf16 into slot 0; h_lstm_0/c_lstm_0 ----
__global__ __launch_bounds__(64) void prologue_kernel(
    const float* __restrict__ xin, const float* __restrict__ h0,
    const float* __restrict__ c0,
    const float* __restrict__ Wgh, const float* __restrict__ bgh,
    const float* __restrict__ Wgc, const float* __restrict__ bgc,
    const float* __restrict__ K, const float* __restrict__ R,
    const float* __restrict__ bl,
    ushort_t* __restrict__ Xt, float* __restrict__ hl, float* __restrict__ cl)
{
    const int n = blockIdx.x;
    const int j = threadIdx.x;
    __shared__ float hs[H_], cs[H_], xs[D_];
    hs[j] = h0[n * H_ + j];
    cs[j] = c0[n * H_ + j];
    if (j < D_) xs[j] = xin[(size_t)n * T_ * D_ + j];
    __syncthreads();

    float xh = bgh[j], xc = bgc[j];
    for (int k = 0; k < H_; k++) {
        xh += hs[k] * Wgh[k * H_ + j];
        xc += cs[k] * Wgc[k * H_ + j];
    }
    Xt[(size_t)j * N_ + n]        = f2bf(xh);
    Xt[(size_t)(H_ + j) * N_ + n] = f2bf(xc);

    float zi = bl[j], zf = bl[H_ + j], zg = bl[2 * H_ + j], zo = bl[3 * H_ + j];
    for (int d = 0; d < D_; d++) {
        float xv = xs[d];
        zi += xv * K[d * 256 + j];
        zf += xv * K[d * 256 + 64 + j];
        zg += xv * K[d * 256 + 128 + j];
        zo += xv * K[d * 256 + 192 + j];
    }
    for (int k = 0; k < H_; k++) {
        float hv = hs[k];
        zi += hv * R[k * 256 + j];
        zf += hv * R[k * 256 + 64 + j];
        zg += hv * R[k * 256 + 128 + j];
        zo += hv * R[k * 256 + 192 + j];
    }
    float clv = sig_(zf) * cs[j] + sig_(zi) * tanh_(zg);
    float hlv = sig_(zo) * tanh_(clv);
    cl[n * H_ + j] = clv;
    hl[n * H_ + j] = hlv;
}

// ---- Persistent kernel: K-split 64 rg x 4 ks, 2 grid barriers/step ----
template<bool DEEP>
__global__ __launch_bounds__(NTHR, 4) void persistent_kernel(
    const ushort_t* __restrict__ Abf,
    ushort_t* __restrict__ Xs,
    const float* __restrict__ hl, const float* __restrict__ clm,
    const float* __restrict__ xin,
    const float* __restrict__ FB,
    float* __restrict__ Pbuf,            // 2 slots x 256 blocks x 4096 f32
    float* __restrict__ oh, float* __restrict__ oc,
    unsigned* __restrict__ cnt)
{
    __shared__ __align__(16) float partB[16384];   // 64 KB: 4 kq planes [32][128]; XBf aliases
    __shared__ __align__(16) float Gs[1024];       // tanh(Y) for own 8 rows x 128
    __shared__ __align__(16) float HLs[512], CLs[512], HNs[512], CNs[512];
    __shared__ __align__(16) float XSs[128];

    const int tid  = threadIdx.x;
    const int bid  = blockIdx.x;
    const int rg   = bid >> 2;           // row-group (32 rows)
    const int ks   = bid & 3;            // K-slice (512 k)
    const int brow32   = rg * 32;
    const int brow_out = brow32 + ks * 8;   // this block's 8 output rows
    const int wave = tid >> 6, lane = tid & 63;
    const int fr   = lane & 15, kg = lane >> 4;
    const int ct   = wave & 3;           // 32-col tile
    const int kq   = wave >> 2;          // 128-k quarter of this block's 512

    // ---- one-time: stage own-row h_lstm/c_lstm (2 KB each) ----
    if (wave == 0) {
        gload16((const char*)(hl + (size_t)brow_out * H_) + lane * 16, (char*)HLs);
        gload16((const char*)(hl + (size_t)brow_out * H_) + 1024 + lane * 16, (char*)HLs + 1024);
    }
    if (wave == 1) {
        gload16((const char*)(clm + (size_t)brow_out * H_) + lane * 16, (char*)CLs);
        gload16((const char*)(clm + (size_t)brow_out * H_) + 1024 + lane * 16, (char*)CLs + 1024);
    }

    // ---- one-time: persistent A fragments (2 M-tiles x 4 iters) ----
    bf16x8 areg[2][4];
    {
        const ushort_t* ab = Abf + (size_t)(brow32 + fr) * N_ + ks * 512 + kq * 128 + kg * 8;
        #pragma unroll
        for (int m = 0; m < 2; m++)
            #pragma unroll
            for (int it = 0; it < 4; it++)
                areg[m][it] = *(const bf16x8*)(ab + (size_t)m * 16 * N_ + it * 32);
    }

    // ---- per-thread epilogue constants ----
    const int c6 = tid & 63;
    const int r8 = (tid >> 6) & 7;
    const int hi = tid >> 9;
    const float bias_a = FB[F_B + hi * 64 + c6];
    float blr0 = 0.f, blr1 = 0.f, blr2 = 0.f, blr3 = 0.f;
    if (tid < 512) {
        blr0 = FB[F_B + 256 + c6];
        blr1 = FB[F_B + 256 + 64 + c6];
        blr2 = FB[F_B + 256 + 128 + c6];
        blr3 = FB[F_B + 256 + 192 + c6];
    }
    __syncthreads();

    for (int t = 0; t < T_; t++) {
        const ushort_t* Xc = Xs + (size_t)(DEEP ? t : (t & 1)) * SLOT_USH;
        ushort_t*       Xn = Xs + (size_t)(DEEP ? (t + 1) : ((t + 1) & 1)) * SLOT_USH;
        float*       Pw = Pbuf + (size_t)(t & 1) * (NBLK * 4096) + (size_t)bid * 4096;
        const float* Pr = Pbuf + (size_t)(t & 1) * (NBLK * 4096);

        // ---- GEMM: 8 B-loads staged upfront, 16 MFMA ----
        f32x4 acc[2][2];
        #pragma unroll
        for (int m = 0; m < 2; m++)
            #pragma unroll
            for (int cc = 0; cc < 2; cc++) acc[m][cc] = (f32x4){0.f, 0.f, 0.f, 0.f};
        {
            const ushort_t* bb = Xc + (size_t)(ct * 32 + fr) * N_ + ks * 512 + kq * 128 + kg * 8;
            bf16x8 b[4][2];
            if constexpr (DEEP) {
                #pragma unroll
                for (int it = 0; it < 4; it++) {
                    b[it][0] = *(const bf16x8*)(bb + it * 32);
                    b[it][1] = *(const bf16x8*)(bb + (size_t)16 * N_ + it * 32);
                }
            } else {
                #pragma unroll
                for (int it = 0; it < 4; it++)
                    #pragma unroll
                    for (int cc = 0; cc < 2; cc++) {
                        const ushort_t* p = bb + (size_t)(cc * 16) * N_ + it * 32;
                        union { unsigned long long q[2]; bf16x8 v; } ub;
                        ub.q[0] = __hip_atomic_load((const unsigned long long*)p,
                                                    __ATOMIC_RELAXED, __HIP_MEMORY_SCOPE_AGENT);
                        ub.q[1] = __hip_atomic_load(((const unsigned long long*)p) + 1,
                                                    __ATOMIC_RELAXED, __HIP_MEMORY_SCOPE_AGENT);
                        b[it][cc] = ub.v;
                    }
            }
            #pragma unroll
            for (int it = 0; it < 4; it++) {
                #pragma unroll
                for (int m = 0; m < 2; m++) {
                    acc[m][0] = __builtin_amdgcn_mfma_f32_16x16x32_bf16(areg[m][it], b[it][0], acc[m][0], 0, 0, 0);
                    acc[m][1] = __builtin_amdgcn_mfma_f32_16x16x32_bf16(areg[m][it], b[it][1], acc[m][1], 0, 0, 0);
                }
            }
        }
        // write partial plane kq (all 32 rows real)
        {
            float* pb = partB + kq * 4096;
            #pragma unroll
            for (int m = 0; m < 2; m++)
                #pragma unroll
                for (int cc = 0; cc < 2; cc++)
                    #pragma unroll
                    for (int r = 0; r < 4; r++)
                        pb[(m * 16 + kg * 4 + r) * 128 + ct * 32 + cc * 16 + fr] = acc[m][cc][r];
        }
        // prefetch x_{t+1} for own 8 rows
        if (t + 1 < T_ && wave == 15 && lane < 32) {
            const float* g = xin + (size_t)(brow_out + (lane >> 2)) * (T_ * D_)
                                 + (size_t)(t + 1) * D_ + (lane & 3) * 4;
            gload16(g, (char*)XSs);
        }
        __syncthreads();

        // ---- reduce 4 kq planes -> store 16 KB partial (agent atomics) ----
        {
            f32x4 s = *(const f32x4*)(partB + tid * 4);
            #pragma unroll
            for (int p = 1; p < 4; p++) s += *(const f32x4*)(partB + p * 4096 + tid * 4);
            union { f32x4 v; unsigned long long q[2]; } u; u.v = s;
            __hip_atomic_store((unsigned long long*)(Pw + tid * 4),     u.q[0],
                               __ATOMIC_RELAXED, __HIP_MEMORY_SCOPE_AGENT);
            __hip_atomic_store((unsigned long long*)(Pw + tid * 4) + 1, u.q[1],
                               __ATOMIC_RELAXED, __HIP_MEMORY_SCOPE_AGENT);
        }
        __syncthreads();   // drain partial stores (vmcnt 0 before s_barrier)

        // ---- grid barrier 1 ----
        if (tid == 0) {
            __hip_atomic_fetch_add(cnt, 1u, __ATOMIC_RELAXED, __HIP_MEMORY_SCOPE_AGENT);
            const unsigned target = (unsigned)NBLK * (unsigned)(t + 1);
            while (__hip_atomic_load(cnt, __ATOMIC_RELAXED, __HIP_MEMORY_SCOPE_AGENT) < target)
                __builtin_amdgcn_s_sleep(1);
        }
        __syncthreads();
        asm volatile("" ::: "memory");

        // ---- gather 4 partners' partials for own 8 rows -> Gs = tanh(Y) ----
        if (tid < 512) {
            const int r = tid >> 6;
            const int c = (tid & 63) * 2;
            float s0 = 0.f, s1 = 0.f;
            #pragma unroll
            for (int p = 0; p < 4; p++) {
                unsigned long long v = __hip_atomic_load(
                    (const unsigned long long*)(Pr + (size_t)(rg * 4 + p) * 4096
                                                + (ks * 8 + r) * 128 + c),
                    __ATOMIC_RELAXED, __HIP_MEMORY_SCOPE_AGENT);
                s0 += __uint_as_float((unsigned)v);
                s1 += __uint_as_float((unsigned)(v >> 32));
            }
            Gs[r * 128 + c]     = tanh_(s0);
            Gs[r * 128 + c + 1] = tanh_(s1);
        }
        __syncthreads();

        // ---- epilogue A: h_new (hi=0) / c_new (hi=1) for own 8 rows ----
        {
            const float* W1 = FB + (hi ? F_CC : F_HC) + c6 * 64;
            const float* W2 = FB + (hi ? F_CP : F_HP) + c6 * 64;
            const float* Sv = hi ? &CLs[r8 * 64] : &HLs[r8 * 64];
            const float* Gv = &Gs[r8 * 128 + hi * 64];
            float a = bias_a;
            #pragma unroll
            for (int kk = 0; kk < 16; kk++) {
                float4 w1 = *(const float4*)(W1 + kk * 4);
                float4 w2 = *(const float4*)(W2 + kk * 4);
                a += w1.x * Sv[kk*4] + w1.y * Sv[kk*4+1] + w1.z * Sv[kk*4+2] + w1.w * Sv[kk*4+3];
                a += w2.x * Gv[kk*4] + w2.y * Gv[kk*4+1] + w2.z * Gv[kk*4+2] + w2.w * Gv[kk*4+3];
            }
            float v = sig_(a);
            (hi ? CNs : HNs)[r8 * 64 + c6] = v;
            float* op = hi ? oc : oh;
            op[(size_t)(brow_out + r8) * (T_ * H_) + (size_t)t * H_ + c6] = v;
        }

        if (t + 1 == T_) break;
        __syncthreads();

        // ---- epilogue B: X_{t+1} premultiplied -> XBf ----
        float* XBf = partB;
        {
            const int j = tid & 127;
            const int r = tid >> 7;     // 0..7
            const float* S = (j < 64) ? &HNs[r * 64] : &CNs[r * 64];
            const float* W = FB + ((j < 64) ? (F_GH + j * 64) : (F_GC + (j - 64) * 64));
            float a = FB[F_B + 128 + j];
            #pragma unroll
            for (int kk = 0; kk < 16; kk++) {
                float4 w = *(const float4*)(W + kk * 4);
                a += w.x * S[kk*4] + w.y * S[kk*4+1] + w.z * S[kk*4+2] + w.w * S[kk*4+3];
            }
            XBf[j * 9 + r] = a;
        }
        __syncthreads();

        // ---- exchange store: X^T bf16, own 8 rows, 8B agent stores ----
        if (tid < 256) {
            const int j    = tid >> 1;
            const int half = tid & 1;
            const float* Xb = &XBf[j * 9 + half * 4];
            unsigned long long v =  (unsigned long long)f2bf(Xb[0])
                                 | ((unsigned long long)f2bf(Xb[1]) << 16)
                                 | ((unsigned long long)f2bf(Xb[2]) << 32)
                                 | ((unsigned long long)f2bf(Xb[3]) << 48);
            __hip_atomic_store((unsigned long long*)(Xn + (size_t)j * N_ + brow_out + half * 4),
                               v, __ATOMIC_RELAXED, __HIP_MEMORY_SCOPE_AGENT);
        }
        __syncthreads();   // drain X stores

        // ---- grid barrier 2 (arrive; hide epilogue C under it; poll) ----
        if (tid == 0)
            __hip_atomic_fetch_add(cnt + 16, 1u, __ATOMIC_RELAXED, __HIP_MEMORY_SCOPE_AGENT);

        if (tid < 512) {
            float z0 = blr0, z1 = blr1, z2 = blr2, z3 = blr3;
            const float* xb = &XSs[r8 * 16];
            const float* hb = &HNs[r8 * 64];
            #pragma unroll
            for (int dd = 0; dd < 4; dd++) {
                float4 w0 = *(const float4*)(FB + F_K + (0 * 64 + c6) * 16 + dd * 4);
                float4 w1 = *(const float4*)(FB + F_K + (1 * 64 + c6) * 16 + dd * 4);
                float4 w2 = *(const float4*)(FB + F_K + (2 * 64 + c6) * 16 + dd * 4);
                float4 w3 = *(const float4*)(FB + F_K + (3 * 64 + c6) * 16 + dd * 4);
                float x0 = xb[dd*4], x1 = xb[dd*4+1], x2 = xb[dd*4+2], x3 = xb[dd*4+3];
                z0 += w0.x*x0 + w0.y*x1 + w0.z*x2 + w0.w*x3;
                z1 += w1.x*x0 + w1.y*x1 + w1.z*x2 + w1.w*x3;
                z2 += w2.x*x0 + w2.y*x1 + w2.z*x2 + w2.w*x3;
                z3 += w3.x*x0 + w3.y*x1 + w3.z*x2 + w3.w*x3;
            }
            #pragma unroll
            for (int kk = 0; kk < 16; kk++) {
                float4 w0 = *(const float4*)(FB + F_R + (0 * 64 + c6) * 64 + kk * 4);
                float4 w1 = *(const float4*)(FB + F_R + (1 * 64 + c6) * 64 + kk * 4);
                float4 w2 = *(const float4*)(FB + F_R + (2 * 64 + c6) * 64 + kk * 4);
                float4 w3 = *(const float4*)(FB + F_R + (3 * 64 + c6) * 64 + kk * 4);
                float h0v = hb[kk*4], h1v = hb[kk*4+1], h2v = hb[kk*4+2], h3v = hb[kk*4+3];
                z0 += w0.x*h0v + w0.y*h1v + w0.z*h2v + w0.w*h3v;
                z1 += w1.x*h0v + w1.y*h1v + w1.z*h2v + w1.w*h3v;
                z2 += w2.x*h0v + w2.y*h1v + w2.z*h2v + w2.w*h3v;
                z3 += w3.x*h0v + w3.y*h1v + w3.z*h2v + w3.w*h3v;
            }
            float clv = sig_(z1) * CNs[r8 * 64 + c6] + sig_(z0) * tanh_(z2);
            float hlv = sig_(z3) * tanh_(clv);
            CLs[r8 * 64 + c6] = clv;
            HLs[r8 * 64 + c6] = hlv;
        }

        if (tid == 0) {
            const unsigned target = (unsigned)NBLK * (unsigned)(t + 1);
            while (__hip_atomic_load(cnt + 16, __ATOMIC_RELAXED, __HIP_MEMORY_SCOPE_AGENT) < target)
                __builtin_amdgcn_s_sleep(1);
        }
        __syncthreads();
        asm volatile("" ::: "memory");
    }
}

extern "C" void kernel_launch(void* const* d_in, const int* in_sizes, int n_in,
                              void* d_out, int out_size, void* d_ws, size_t ws_size,
                              hipStream_t stream) {
    const float* xin = (const float*)d_in[0];
    const float* h0  = (const float*)d_in[1];
    const float* c0  = (const float*)d_in[2];
    const float* A   = (const float*)d_in[3];
    const float* Wgh = (const float*)d_in[4];
    const float* bgh = (const float*)d_in[5];
    const float* Wgc = (const float*)d_in[6];
    const float* bgc = (const float*)d_in[7];
    const float* Whc = (const float*)d_in[8];
    const float* Whp = (const float*)d_in[9];
    const float* bh  = (const float*)d_in[10];
    const float* Wcc = (const float*)d_in[11];
    const float* Wcp = (const float*)d_in[12];
    const float* bc  = (const float*)d_in[13];
    const float* K   = (const float*)d_in[14];
    const float* R   = (const float*)d_in[15];
    const float* bl  = (const float*)d_in[16];

    const size_t pbuf_bytes = (size_t)2 * NBLK * 4096 * 4;   // 8 MB
    const size_t fixed = (size_t)N_ * N_ * 2
                       + (size_t)N_ * H_ * 4 * 2
                       + (size_t)FBLOB_F32 * 4
                       + pbuf_bytes + 256;
    const size_t slot_bytes = SLOT_USH * 2;
    const bool deep = ws_size >= fixed + (size_t)(T_ + 1) * slot_bytes;
    const int nslots = deep ? (T_ + 1) : 2;

    char* w = (char*)d_ws;
    ushort_t* Abf  = (ushort_t*)w;  w += (size_t)N_ * N_ * 2;
    ushort_t* Xs   = (ushort_t*)w;  w += (size_t)nslots * slot_bytes;
    float* hl      = (float*)w;     w += (size_t)N_ * H_ * 4;
    float* cl      = (float*)w;     w += (size_t)N_ * H_ * 4;
    float* fblob   = (float*)w;     w += (size_t)FBLOB_F32 * 4;
    float* Pbuf    = (float*)w;     w += pbuf_bytes;
    unsigned* cnt  = (unsigned*)w;  w += 256;

    float* oh = (float*)d_out;
    float* oc = oh + (size_t)N_ * T_ * H_;

    convert_A_kernel<<<(N_ * N_) / (256 * 4), 256, 0, stream>>>(A, Abf, cnt);
    convert_Wf_kernel<<<16, 256, 0, stream>>>(Whc, Whp, Wcc, Wcp, Wgh, Wgc, R, K,
                                              bh, bc, bgh, bgc, bl, fblob);
    prologue_kernel<<<N_, 64, 0, stream>>>(xin, h0, c0, Wgh, bgh, Wgc, bgc,
                                           K, R, bl, Xs, hl, cl);

    void* args[] = { (void*)&Abf, (void*)&Xs, (void*)&hl, (void*)&cl,
                     (void*)&xin, (void*)&fblob, (void*)&Pbuf,
                     (void*)&oh, (void*)&oc, (void*)&cnt };
    if (deep)
        hipLaunchCooperativeKernel((const void*)persistent_kernel<true>,
                                   dim3(NBLK), dim3(NTHR), args, 0, stream);
    else
        hipLaunchCooperativeKernel((const void*)persistent_kernel<false>,
                                   dim3(NBLK), dim3(NTHR), args, 0, stream);
}